// Round 2
// baseline (172.266 us; speedup 1.0000x reference)
//
#include <hip/hip_runtime.h>
#include <stdint.h>

#define A_DIM 8192
#define B_DIM 8192
#define K_CL  256
#define MROWS 32           // rows per block
#define NW    8            // waves per block
#define WKV   (B_DIM / NW) // 1024 k-columns per wave
#define NKS   (WKV / 32)   // 32 K-steps of K=32

typedef short bf16x8 __attribute__((ext_vector_type(8)));
typedef float f32x4  __attribute__((ext_vector_type(4)));

__device__ __forceinline__ unsigned short f2bf(float f) {
    unsigned int u = __float_as_uint(f);
    u += 0x7fffu + ((u >> 16) & 1u);   // RNE (finite inputs)
    return (unsigned short)(u >> 16);
}

__device__ __forceinline__ bf16x8 pack8(float4 a, float4 b) {
    union { bf16x8 v; unsigned int u[4]; } r;
    r.u[0] = (unsigned int)f2bf(a.x) | ((unsigned int)f2bf(a.y) << 16);
    r.u[1] = (unsigned int)f2bf(a.z) | ((unsigned int)f2bf(a.w) << 16);
    r.u[2] = (unsigned int)f2bf(b.x) | ((unsigned int)f2bf(b.y) << 16);
    r.u[3] = (unsigned int)f2bf(b.z) | ((unsigned int)f2bf(b.w) << 16);
    return r.v;
}

// ---------- fused prep: blocks 0..511 transpose p_r -> prT bf16; 512..767 pl_dot ----------
__global__ __launch_bounds__(256) void k_prep(const float* __restrict__ pr,
                                              const float* __restrict__ pl,
                                              const float* __restrict__ cp,
                                              unsigned short* __restrict__ prT,
                                              float* __restrict__ pl_dot) {
    if (blockIdx.x < 512) {
        __shared__ unsigned short lt[64][66];
        const int bidb = blockIdx.x >> 2;
        const int bidk = blockIdx.x & 3;
        const int b0 = bidb * 64, k0 = bidk * 64;
        const int t = threadIdx.x;
        const int tr = t >> 4, tc = t & 15;
#pragma unroll
        for (int q = 0; q < 4; q++) {
            int brow = q * 16 + tr;
            const float4 v = *(const float4*)(pr + (size_t)(b0 + brow) * K_CL + k0 + tc * 4);
            lt[tc * 4 + 0][brow] = f2bf(v.x);
            lt[tc * 4 + 1][brow] = f2bf(v.y);
            lt[tc * 4 + 2][brow] = f2bf(v.z);
            lt[tc * 4 + 3][brow] = f2bf(v.w);
        }
        __syncthreads();
#pragma unroll
        for (int q = 0; q < 4; q++) {
            int krow = q * 16 + tr;
            ushort4 o;
            o.x = lt[krow][tc * 4 + 0];
            o.y = lt[krow][tc * 4 + 1];
            o.z = lt[krow][tc * 4 + 2];
            o.w = lt[krow][tc * 4 + 3];
            *(ushort4*)(prT + (size_t)(k0 + krow) * B_DIM + b0 + tc * 4) = o;
        }
    } else {
        const int row0 = (blockIdx.x - 512) * 32;
        const int r = threadIdx.x >> 3, sub = threadIdx.x & 7;
        const float* prow = pl + (size_t)(row0 + r) * K_CL + sub * 32;
        const float* cpr = cp + sub * 32;
        float v = 0.f;
#pragma unroll
        for (int q = 0; q < 8; q++) {
            float4 x = *(const float4*)(prow + q * 4);
            float4 c = *(const float4*)(cpr + q * 4);
            v += x.x / c.x + x.y / c.y + x.z / c.z + x.w / c.w;
        }
        v += __shfl_xor(v, 1, 64);
        v += __shfl_xor(v, 2, 64);
        v += __shfl_xor(v, 4, 64);
        if (sub == 0) pl_dot[row0 + r] = v;
    }
}

// ---------- main: barrier-free split-M GEMM-reduce ----------
__global__ __launch_bounds__(512, 2) void k_main(const float* __restrict__ w,
                                                 const float* __restrict__ pl,
                                                 const unsigned short* __restrict__ prT,
                                                 const float* __restrict__ cp,
                                                 const float* __restrict__ pl_dot,
                                                 float* __restrict__ out) {
    __shared__ float coef[MROWS][260];   // (1-2*pl)/cp, padded stride
    __shared__ float pld_s[MROWS];
    __shared__ float red[NW];

    const int m0 = blockIdx.x * MROWS;
    const int tid = threadIdx.x;
    const int lane = tid & 63;
    const int wv = tid >> 6;

    // stage coef block [32][256] once
    {
        const int r = tid >> 4;
        const int n0 = (tid & 15) * 16;
        const float* plr = pl + (size_t)(m0 + r) * K_CL + n0;
        const float* cpr = cp + n0;
#pragma unroll
        for (int q = 0; q < 4; q++) {
            float4 v = *(const float4*)(plr + q * 4);
            float4 c = *(const float4*)(cpr + q * 4);
            coef[r][n0 + q * 4 + 0] = (1.f - 2.f * v.x) / c.x;
            coef[r][n0 + q * 4 + 1] = (1.f - 2.f * v.y) / c.y;
            coef[r][n0 + q * 4 + 2] = (1.f - 2.f * v.z) / c.z;
            coef[r][n0 + q * 4 + 3] = (1.f - 2.f * v.w) / c.w;
        }
    }
    if (tid < MROWS) pld_s[tid] = pl_dot[m0 + tid];
    __syncthreads();

    const int l15 = lane & 15, lg = lane >> 4;
    const float pld0 = pld_s[l15];
    const float pld1 = pld_s[16 + l15];

    const int kbase = wv * WKV;
    const float* wrow0 = w + (size_t)(m0 + l15) * B_DIM + kbase + lg * 8;
    const float* wrow1 = wrow0 + (size_t)16 * B_DIM;
    const unsigned short* pb = prT + (size_t)l15 * B_DIM + kbase + lg * 8;

    f32x4 zero = {0.f, 0.f, 0.f, 0.f};
    f32x4 acc[2][16];
#pragma unroll
    for (int mi = 0; mi < 2; mi++)
#pragma unroll
        for (int ni = 0; ni < 16; ni++) acc[mi][ni] = zero;

    float rs = 0.f;

    float4 wA0, wA1, wA2, wA3, wB0, wB1, wB2, wB3;

    auto loadA = [&](int ks, float4& x0, float4& x1, float4& x2, float4& x3) {
        const float* p0 = wrow0 + ks * 32;
        const float* p1 = wrow1 + ks * 32;
        x0 = *(const float4*)p0;
        x1 = *(const float4*)(p0 + 4);
        x2 = *(const float4*)p1;
        x3 = *(const float4*)(p1 + 4);
    };

    auto computeK = [&](int ks, float4 x0, float4 x1, float4 x2, float4 x3) {
        float s0 = x0.x + x0.y + x0.z + x0.w + x1.x + x1.y + x1.z + x1.w;
        float s1 = x2.x + x2.y + x2.z + x2.w + x3.x + x3.y + x3.z + x3.w;
        rs += s0 * pld0 + s1 * pld1;
        bf16x8 a0 = pack8(x0, x1);
        bf16x8 a1 = pack8(x2, x3);
        const unsigned short* pk = pb + ks * 32;
#pragma unroll
        for (int g = 0; g < 2; g++) {
            bf16x8 b[8];
#pragma unroll
            for (int j = 0; j < 8; j++)
                b[j] = *(const bf16x8*)(pk + (size_t)(g * 8 + j) * 16 * B_DIM);
#pragma unroll
            for (int j = 0; j < 8; j++) {
                acc[0][g * 8 + j] = __builtin_amdgcn_mfma_f32_16x16x32_bf16(a0, b[j], acc[0][g * 8 + j], 0, 0, 0);
                acc[1][g * 8 + j] = __builtin_amdgcn_mfma_f32_16x16x32_bf16(a1, b[j], acc[1][g * 8 + j], 0, 0, 0);
            }
        }
    };

    loadA(0, wA0, wA1, wA2, wA3);
    for (int ks = 0; ks < NKS; ks += 2) {
        loadA(ks + 1, wB0, wB1, wB2, wB3);
        computeK(ks, wA0, wA1, wA2, wA3);
        if (ks + 2 < NKS) loadA(ks + 2, wA0, wA1, wA2, wA3);
        computeK(ks + 1, wB0, wB1, wB2, wB3);
    }

    // epilogue: apply coef to own accumulator
    float tot = rs;
#pragma unroll
    for (int mi = 0; mi < 2; mi++) {
#pragma unroll
        for (int r = 0; r < 4; r++) {
            const int lrow = mi * 16 + lg * 4 + r;
#pragma unroll
            for (int ni = 0; ni < 16; ni++) {
                const int n = ni * 16 + l15;
                tot += acc[mi][ni][r] * coef[lrow][n];
            }
        }
    }
    for (int o = 32; o; o >>= 1) tot += __shfl_down(tot, o, 64);
    if (lane == 0) red[wv] = tot;
    __syncthreads();
    if (tid == 0) {
        float s = 0.f;
#pragma unroll
        for (int i = 0; i < NW; i++) s += red[i];
        atomicAdd(out, s);
    }
}

extern "C" void kernel_launch(void* const* d_in, const int* in_sizes, int n_in,
                              void* d_out, int out_size, void* d_ws, size_t ws_size,
                              hipStream_t stream) {
    const float* w  = (const float*)d_in[0];
    const float* pl = (const float*)d_in[1];
    const float* pr = (const float*)d_in[2];
    const float* cp = (const float*)d_in[3];
    float* out = (float*)d_out;

    unsigned short* prT = (unsigned short*)d_ws;                          // 4 MB
    float* pl_dot = (float*)((char*)d_ws + (size_t)K_CL * B_DIM * 2);     // +32 KB

    hipMemsetAsync(d_out, 0, sizeof(float), stream);
    k_prep<<<dim3(768), dim3(256), 0, stream>>>(pr, pl, cp, prT, pl_dot);
    k_main<<<dim3(A_DIM / MROWS), dim3(512), 0, stream>>>(w, pl, prT, cp, pl_dot, out);
}

// Round 3
// 89.003 us; speedup vs baseline: 1.9355x; 1.9355x over previous
//
#include <hip/hip_runtime.h>
#include <stdint.h>

#define A_DIM 8192
#define B_DIM 8192
#define K_CL  256
#define BM    64
#define BK    64
#define NSLAB 4
#define SLABW (B_DIM / NSLAB)   // 2048
#define NKS   (SLABW / BK)      // 32

typedef short bf16x8 __attribute__((ext_vector_type(8)));
typedef float f32x4  __attribute__((ext_vector_type(4)));
typedef unsigned short u16;

__device__ __forceinline__ u16 f2bf(float f) {
    unsigned int u = __float_as_uint(f);
    u += 0x7fffu + ((u >> 16) & 1u);   // RNE, finite inputs
    return (u16)(u >> 16);
}

// ---------- prep ----------
// blocks 0..255:  pack p_r into MFMA B-fragment layout, bf16:
//   Bpack[((kb*16 + c)*64 + lane)*8 + j] = bf16(p_r[kb*32 + (lane>>4)*8 + j][c*16 + (lane&15)])
// blocks 256..511: pl_dot[a] = sum_k p_l[a,k]/cp[k]
__global__ __launch_bounds__(256) void k_prep(const float* __restrict__ pr,
                                              const float* __restrict__ pl,
                                              const float* __restrict__ cp,
                                              u16* __restrict__ Bpack,
                                              float* __restrict__ pl_dot) {
    const int t = threadIdx.x;
    if (blockIdx.x < 256) {
        const int kb = blockIdx.x;
        const int lane = t & 63, wv = t >> 6;
        const int lg = lane >> 4, l15 = lane & 15;
#pragma unroll
        for (int ci = 0; ci < 4; ci++) {
            const int c = wv * 4 + ci;
            float v[8];
#pragma unroll
            for (int j = 0; j < 8; j++)
                v[j] = pr[(size_t)(kb * 32 + lg * 8 + j) * K_CL + c * 16 + l15];
            union { bf16x8 b; unsigned int u[4]; } o;
#pragma unroll
            for (int j = 0; j < 4; j++)
                o.u[j] = (unsigned int)f2bf(v[2 * j]) | ((unsigned int)f2bf(v[2 * j + 1]) << 16);
            *(bf16x8*)(Bpack + ((size_t)(kb * 16 + c) * 64 + lane) * 8) = o.b;
        }
    } else {
        const int row0 = (blockIdx.x - 256) * 32;
        const int r = t >> 3, sub = t & 7;
        const float* prow = pl + (size_t)(row0 + r) * K_CL + sub * 32;
        const float* cpr = cp + sub * 32;
        float v = 0.f;
#pragma unroll
        for (int q = 0; q < 8; q++) {
            float4 x = *(const float4*)(prow + q * 4);
            float4 c = *(const float4*)(cpr + q * 4);
            v += x.x / c.x + x.y / c.y + x.z / c.z + x.w / c.w;
        }
        v += __shfl_xor(v, 1, 64);
        v += __shfl_xor(v, 2, 64);
        v += __shfl_xor(v, 4, 64);
        if (sub == 0) pl_dot[row0 + r] = v;
    }
}

// ---------- main ----------
__global__ __launch_bounds__(256, 2) void k_main(const float* __restrict__ w,
                                                 const float* __restrict__ pl,
                                                 const u16* __restrict__ Bpack,
                                                 const float* __restrict__ cp,
                                                 const float* __restrict__ pl_dot,
                                                 float* __restrict__ out) {
    __shared__ float Abuf[2][BM * BK];   // 2 x 16 KB, row = 256 B, source-swizzled
    __shared__ float pld_s[BM];
    __shared__ float red[4];

    const int bid = blockIdx.x;
    const int slab = bid & 3;
    const int m0 = (bid >> 2) * BM;
    const int tid = threadIdx.x;
    const int lane = tid & 63, wv = tid >> 6;
    const int lg = lane >> 4, l15 = lane & 15;

    if (tid < BM) pld_s[tid] = pl_dot[m0 + tid];

    float rcp_cp[4];
#pragma unroll
    for (int ni = 0; ni < 4; ni++)
        rcp_cp[ni] = 1.0f / cp[wv * 64 + ni * 16 + l15];

    __syncthreads();                       // pld_s ready; drains everything (prologue only)
    float pld[4];
#pragma unroll
    for (int mi = 0; mi < 4; mi++)
        pld[mi] = (wv == 0) ? pld_s[mi * 16 + l15] : 0.f;   // only wave 0 accumulates row-sum term

    const char* wbase = (const char*)(w + (size_t)m0 * B_DIM + (size_t)slab * SLABW);

    // stage [64 rows][64 f32] of w into Abuf[buf] via global_load_lds (linear dest,
    // inverse-XOR-swizzled per-lane SOURCE so reads can use the swizzled offsets)
    auto stage = [&](int buf, int ks) {
#pragma unroll
        for (int i = 0; i < 4; i++) {
            const int row_local = wv * 16 + i * 4 + lg;
            const int sw = (row_local & 7) << 4;
            const char* src = wbase + (size_t)row_local * (B_DIM * 4) + ks * 256 + ((l15 * 16) ^ sw);
            void* dst = (void*)&Abuf[buf][(wv * 16 + i * 4) * BK];
            __builtin_amdgcn_global_load_lds(
                (const __attribute__((address_space(1))) void*)src,
                (__attribute__((address_space(3))) void*)dst, 16, 0, 0);
        }
    };

    f32x4 acc[4][4];
#pragma unroll
    for (int mi = 0; mi < 4; mi++)
#pragma unroll
        for (int ni = 0; ni < 4; ni++) {
            f32x4 z = {0.f, 0.f, 0.f, 0.f};
            acc[mi][ni] = z;
        }

    float rs = 0.f;

    stage(0, 0);   // outstanding: 4

    const u16* bslab = Bpack + (size_t)slab * 64 * 8192;   // 64 kb-blocks * 16 KB each

    for (int ks = 0; ks < NKS; ++ks) {
        const int cur = ks & 1;

        // 1. issue 8 B-fragment loads (L2-resident, fully coalesced 1 KB each)
        bf16x8 b0[4], b1[4];
        const u16* bp = bslab + (size_t)ks * 2 * 8192;
#pragma unroll
        for (int ni = 0; ni < 4; ni++)
            b0[ni] = *(const bf16x8*)(bp + (size_t)(wv * 4 + ni) * 512 + lane * 8);
#pragma unroll
        for (int ni = 0; ni < 4; ni++)
            b1[ni] = *(const bf16x8*)(bp + (size_t)(16 + wv * 4 + ni) * 512 + lane * 8);

        // 2. counted wait: oldest 4 (stage(ks)) done; 8 B-loads stay in flight
        asm volatile("s_waitcnt vmcnt(8)" ::: "memory");
        // 3. raw barrier: buf[cur] valid for all waves; everyone done reading buf[cur^1]
        __builtin_amdgcn_s_barrier();
        __builtin_amdgcn_sched_barrier(0);

        // 4. prefetch next A tile into the other buffer (stays in flight across next barrier)
        if (ks + 1 < NKS) stage(cur ^ 1, ks + 1);

        // 5. compute: LDS f32 -> bf16 frags -> MFMA; compiler inserts counted vmcnt for b0/b1
        const char* abase = (const char*)&Abuf[cur][0];
#pragma unroll
        for (int h = 0; h < 2; h++) {
#pragma unroll
            for (int mi = 0; mi < 4; mi++) {
                const int row = mi * 16 + l15;
                const int sw = (row & 7) << 4;
                const char* rp = abase + row * 256;
                f32x4 f0 = *(const f32x4*)(rp + ((h * 128 + lg * 32) ^ sw));
                f32x4 f1 = *(const f32x4*)(rp + ((h * 128 + lg * 32 + 16) ^ sw));
                rs += (f0[0] + f0[1] + f0[2] + f0[3] + f1[0] + f1[1] + f1[2] + f1[3]) * pld[mi];
                union { bf16x8 v; unsigned int u[4]; } a;
                a.u[0] = (unsigned int)f2bf(f0[0]) | ((unsigned int)f2bf(f0[1]) << 16);
                a.u[1] = (unsigned int)f2bf(f0[2]) | ((unsigned int)f2bf(f0[3]) << 16);
                a.u[2] = (unsigned int)f2bf(f1[0]) | ((unsigned int)f2bf(f1[1]) << 16);
                a.u[3] = (unsigned int)f2bf(f1[2]) | ((unsigned int)f2bf(f1[3]) << 16);
#pragma unroll
                for (int ni = 0; ni < 4; ni++)
                    acc[mi][ni] = __builtin_amdgcn_mfma_f32_16x16x32_bf16(
                        a.v, (h == 0) ? b0[ni] : b1[ni], acc[mi][ni], 0, 0, 0);
            }
        }
    }

    // epilogue: tot = rs + sum Q * (1 - 2*pl)/cp   (C/D: col=lane&15, row=(lane>>4)*4+r)
    float tot = rs;
#pragma unroll
    for (int mi = 0; mi < 4; mi++) {
#pragma unroll
        for (int r = 0; r < 4; r++) {
            const float* plrow = pl + (size_t)(m0 + mi * 16 + lg * 4 + r) * K_CL + wv * 64 + l15;
#pragma unroll
            for (int ni = 0; ni < 4; ni++)
                tot += acc[mi][ni][r] * (1.0f - 2.0f * plrow[ni * 16]) * rcp_cp[ni];
        }
    }
    for (int o = 32; o; o >>= 1) tot += __shfl_down(tot, o, 64);
    if (lane == 0) red[wv] = tot;
    __syncthreads();
    if (tid == 0) atomicAdd(out, red[0] + red[1] + red[2] + red[3]);
}

extern "C" void kernel_launch(void* const* d_in, const int* in_sizes, int n_in,
                              void* d_out, int out_size, void* d_ws, size_t ws_size,
                              hipStream_t stream) {
    const float* w  = (const float*)d_in[0];
    const float* pl = (const float*)d_in[1];
    const float* pr = (const float*)d_in[2];
    const float* cp = (const float*)d_in[3];
    float* out = (float*)d_out;

    u16* Bpack = (u16*)d_ws;                                      // 4 MB
    float* pl_dot = (float*)((char*)d_ws + (size_t)4 * 1024 * 1024);

    hipMemsetAsync(d_out, 0, sizeof(float), stream);
    k_prep<<<dim3(512), dim3(256), 0, stream>>>(pr, pl, cp, Bpack, pl_dot);
    k_main<<<dim3(128 * NSLAB), dim3(256), 0, stream>>>(w, pl, Bpack, cp, pl_dot, out);
}

// Round 4
// 72.618 us; speedup vs baseline: 2.3722x; 1.2256x over previous
//
#include <hip/hip_runtime.h>
#include <stdint.h>

#define A_DIM 8192
#define B_DIM 8192
#define K_CL  256
#define BM    64
#define BK    64
#define NSLAB 4
#define SLABW (B_DIM / NSLAB)   // 2048
#define NKS   (SLABW / BK)      // 32

typedef short bf16x8 __attribute__((ext_vector_type(8)));
typedef float f32x4  __attribute__((ext_vector_type(4)));
typedef unsigned short u16;

__device__ __forceinline__ u16 f2bf(float f) {
    unsigned int u = __float_as_uint(f);
    u += 0x7fffu + ((u >> 16) & 1u);   // RNE, finite inputs (prep only)
    return (u16)(u >> 16);
}

// ---------- prep ----------
// blocks 0..255:  pack p_r into MFMA B-fragment layout, bf16 (RNE):
//   Bpack[((kb*16 + c)*64 + lane)*8 + j] = bf16(p_r[kb*32 + (lane>>4)*8 + j][c*16 + (lane&15)])
// blocks 256..511: pl_dot[a] = sum_k p_l[a,k]/cp[k]; block 256 also zeroes out.
__global__ __launch_bounds__(256) void k_prep(const float* __restrict__ pr,
                                              const float* __restrict__ pl,
                                              const float* __restrict__ cp,
                                              u16* __restrict__ Bpack,
                                              float* __restrict__ pl_dot,
                                              float* __restrict__ out) {
    const int t = threadIdx.x;
    if (blockIdx.x < 256) {
        const int kb = blockIdx.x;
        const int lane = t & 63, wv = t >> 6;
        const int lg = lane >> 4, l15 = lane & 15;
#pragma unroll
        for (int ci = 0; ci < 4; ci++) {
            const int c = wv * 4 + ci;
            float v[8];
#pragma unroll
            for (int j = 0; j < 8; j++)
                v[j] = pr[(size_t)(kb * 32 + lg * 8 + j) * K_CL + c * 16 + l15];
            union { bf16x8 b; unsigned int u[4]; } o;
#pragma unroll
            for (int j = 0; j < 4; j++)
                o.u[j] = (unsigned int)f2bf(v[2 * j]) | ((unsigned int)f2bf(v[2 * j + 1]) << 16);
            *(bf16x8*)(Bpack + ((size_t)(kb * 16 + c) * 64 + lane) * 8) = o.b;
        }
    } else {
        if (blockIdx.x == 256 && t == 0) out[0] = 0.0f;
        const int row0 = (blockIdx.x - 256) * 32;
        const int r = t >> 3, sub = t & 7;
        const float* prow = pl + (size_t)(row0 + r) * K_CL + sub * 32;
        const float* cpr = cp + sub * 32;
        float v = 0.f;
#pragma unroll
        for (int q = 0; q < 8; q++) {
            float4 x = *(const float4*)(prow + q * 4);
            float4 c = *(const float4*)(cpr + q * 4);
            v += x.x / c.x + x.y / c.y + x.z / c.z + x.w / c.w;
        }
        v += __shfl_xor(v, 1, 64);
        v += __shfl_xor(v, 2, 64);
        v += __shfl_xor(v, 4, 64);
        if (sub == 0) pl_dot[row0 + r] = v;
    }
}

// ---------- main ----------
__global__ __launch_bounds__(256, 2) void k_main(const float* __restrict__ w,
                                                 const float* __restrict__ pl,
                                                 const u16* __restrict__ Bpack,
                                                 const float* __restrict__ cp,
                                                 const float* __restrict__ pl_dot,
                                                 float* __restrict__ out) {
    __shared__ float Abuf[4][BM * BK];   // 4 x 16 KB, row = 256 B, source-swizzled
    __shared__ float pld_s[BM];
    __shared__ float red[4];

    const int bid = blockIdx.x;
    const int slab = bid & 3;
    const int m0 = (bid >> 2) * BM;
    const int tid = threadIdx.x;
    const int lane = tid & 63, wv = tid >> 6;
    const int lg = lane >> 4, l15 = lane & 15;

    if (tid < BM) pld_s[tid] = pl_dot[m0 + tid];

    float rcp_cp[4];
#pragma unroll
    for (int ni = 0; ni < 4; ni++)
        rcp_cp[ni] = 1.0f / cp[wv * 64 + ni * 16 + l15];

    __syncthreads();                       // pld_s ready (prologue only)
    float pld[4];
#pragma unroll
    for (int mi = 0; mi < 4; mi++) pld[mi] = pld_s[mi * 16 + l15];   // consumed by wave 0 only

    const char* wbase = (const char*)(w + (size_t)m0 * B_DIM + (size_t)slab * SLABW);

    // stage [64 rows][64 f32] of w via global_load_lds: linear LDS dest,
    // inverse-XOR-swizzled per-lane global SOURCE (both-sides swizzle rule)
    auto stage = [&](int buf, int ks) {
#pragma unroll
        for (int i = 0; i < 4; i++) {
            const int row_local = wv * 16 + i * 4 + lg;
            const int sw = (row_local & 7) << 4;
            const char* src = wbase + (size_t)row_local * (B_DIM * 4) + ks * 256 + ((l15 * 16) ^ sw);
            void* dst = (void*)&Abuf[buf][(wv * 16 + i * 4) * BK];
            __builtin_amdgcn_global_load_lds(
                (const __attribute__((address_space(1))) void*)src,
                (__attribute__((address_space(3))) void*)dst, 16, 0, 0);
        }
    };

    const u16* bslab = Bpack + (size_t)slab * 64 * 8192;

#define LOADB(arr, ks) do {                                                          \
        const u16* bp_ = bslab + (size_t)(ks) * 2 * 8192;                            \
        _Pragma("unroll")                                                            \
        for (int ni_ = 0; ni_ < 4; ni_++)                                            \
            arr[ni_] = *(const bf16x8*)(bp_ + (size_t)(wv * 4 + ni_) * 512 + lane * 8); \
        _Pragma("unroll")                                                            \
        for (int ni_ = 0; ni_ < 4; ni_++)                                            \
            arr[4 + ni_] = *(const bf16x8*)(bp_ + (size_t)(16 + wv * 4 + ni_) * 512 + lane * 8); \
    } while (0)

#define COMPUTE(cur, arr) do {                                                       \
        const char* abase_ = (const char*)&Abuf[(cur)][0];                           \
        _Pragma("unroll")                                                            \
        for (int h_ = 0; h_ < 2; h_++) {                                             \
            _Pragma("unroll")                                                        \
            for (int mi_ = 0; mi_ < 4; mi_++) {                                      \
                const int row_ = mi_ * 16 + l15;                                     \
                const int sw_ = (row_ & 7) << 4;                                     \
                const char* rp_ = abase_ + row_ * 256;                               \
                f32x4 f0_ = *(const f32x4*)(rp_ + ((h_ * 128 + lg * 32) ^ sw_));     \
                f32x4 f1_ = *(const f32x4*)(rp_ + ((h_ * 128 + lg * 32 + 16) ^ sw_));\
                if (wv == 0)                                                         \
                    sums[mi_] += f0_[0]+f0_[1]+f0_[2]+f0_[3]+f1_[0]+f1_[1]+f1_[2]+f1_[3]; \
                union { bf16x8 v; unsigned int u[4]; } a_;                           \
                a_.u[0] = __builtin_amdgcn_perm(__float_as_uint(f0_[1]), __float_as_uint(f0_[0]), 0x07060302u); \
                a_.u[1] = __builtin_amdgcn_perm(__float_as_uint(f0_[3]), __float_as_uint(f0_[2]), 0x07060302u); \
                a_.u[2] = __builtin_amdgcn_perm(__float_as_uint(f1_[1]), __float_as_uint(f1_[0]), 0x07060302u); \
                a_.u[3] = __builtin_amdgcn_perm(__float_as_uint(f1_[3]), __float_as_uint(f1_[2]), 0x07060302u); \
                _Pragma("unroll")                                                    \
                for (int ni_ = 0; ni_ < 4; ni_++)                                    \
                    acc[mi_][ni_] = __builtin_amdgcn_mfma_f32_16x16x32_bf16(         \
                        a_.v, (arr)[h_ * 4 + ni_], acc[mi_][ni_], 0, 0, 0);          \
            }                                                                        \
        }                                                                            \
    } while (0)

#define BODY(ks, WAITN, BCUR, BNXT, DOSTAGE, DOLOADB) do {                           \
        asm volatile("s_waitcnt vmcnt(" #WAITN ")" ::: "memory");                    \
        __builtin_amdgcn_s_barrier();                                                \
        __builtin_amdgcn_sched_barrier(0);                                           \
        if (DOLOADB) LOADB(BNXT, (ks) + 1);                                          \
        if (DOSTAGE) stage(((ks) + 3) & 3, (ks) + 3);                                \
        COMPUTE((ks) & 3, BCUR);                                                     \
    } while (0)

    f32x4 acc[4][4];
#pragma unroll
    for (int mi = 0; mi < 4; mi++)
#pragma unroll
        for (int ni = 0; ni < 4; ni++) {
            f32x4 z = {0.f, 0.f, 0.f, 0.f};
            acc[mi][ni] = z;
        }
    float sums[4] = {0.f, 0.f, 0.f, 0.f};

    bf16x8 bA[8], bB[8];
    stage(0, 0); stage(1, 1); stage(2, 2);
    LOADB(bA, 0);

    for (int ks = 0; ks < NKS - 4; ks += 2) {   // ks = 0..27
        BODY(ks,     16, bA, bB, 1, 1);
        BODY(ks + 1, 16, bB, bA, 1, 1);
    }
    BODY(28, 16, bA, bB, 1, 1);   // stages S31, loads B29
    BODY(29, 16, bB, bA, 0, 1);   // loads B30
    BODY(30, 12, bA, bB, 0, 1);   // loads B31
    BODY(31,  8, bB, bA, 0, 0);

#undef BODY
#undef COMPUTE
#undef LOADB

    // epilogue: tot = rs + sum Q * (1 - 2*pl)/cp   (C/D: col=lane&15, row=(lane>>4)*4+r)
    float tot = 0.f;
    if (wv == 0) {
#pragma unroll
        for (int mi = 0; mi < 4; mi++) tot += sums[mi] * pld[mi];
    }
#pragma unroll
    for (int mi = 0; mi < 4; mi++) {
#pragma unroll
        for (int r = 0; r < 4; r++) {
            const float* plrow = pl + (size_t)(m0 + mi * 16 + lg * 4 + r) * K_CL + wv * 64 + l15;
#pragma unroll
            for (int ni = 0; ni < 4; ni++)
                tot += acc[mi][ni][r] * (1.0f - 2.0f * plrow[ni * 16]) * rcp_cp[ni];
        }
    }
    for (int o = 32; o; o >>= 1) tot += __shfl_down(tot, o, 64);
    if (lane == 0) red[wv] = tot;
    __syncthreads();
    if (tid == 0) atomicAdd(out, red[0] + red[1] + red[2] + red[3]);
}

extern "C" void kernel_launch(void* const* d_in, const int* in_sizes, int n_in,
                              void* d_out, int out_size, void* d_ws, size_t ws_size,
                              hipStream_t stream) {
    const float* w  = (const float*)d_in[0];
    const float* pl = (const float*)d_in[1];
    const float* pr = (const float*)d_in[2];
    const float* cp = (const float*)d_in[3];
    float* out = (float*)d_out;

    u16* Bpack = (u16*)d_ws;                                      // 4 MB
    float* pl_dot = (float*)((char*)d_ws + (size_t)4 * 1024 * 1024);

    k_prep<<<dim3(512), dim3(256), 0, stream>>>(pr, pl, cp, Bpack, pl_dot, out);
    k_main<<<dim3(128 * NSLAB), dim3(256), 0, stream>>>(w, pl, Bpack, cp, pl_dot, out);
}